// Round 5
// baseline (162.738 us; speedup 1.0000x reference)
//
#include <hip/hip_runtime.h>

typedef __attribute__((ext_vector_type(4))) _Float16 half4;
typedef __attribute__((ext_vector_type(8))) _Float16 half8;
typedef __attribute__((ext_vector_type(4))) float f32x4;

#define T_STEPS 24
#define N_NODES 325
#define RS_T 20800       // N*H elements per t
#define B_STRIDE 499200  // T*N*H elements per b
#define HLAST_OFF 31948800

__device__ __forceinline__ float fsigmoid(float x) {
    return __builtin_amdgcn_rcpf(1.0f + __expf(-x));
}
__device__ __forceinline__ float ftanh_f(float x) {
    return 1.0f - 2.0f * __builtin_amdgcn_rcpf(1.0f + __expf(2.0f * x));
}
__device__ __forceinline__ half4 cvt4(f32x4 a) {
    half4 r;
    r[0] = (_Float16)a[0]; r[1] = (_Float16)a[1];
    r[2] = (_Float16)a[2]; r[3] = (_Float16)a[3];
    return r;
}
__device__ __forceinline__ half8 cvt8(f32x4 a, f32x4 b) {
    half8 r;
    r[0]=(_Float16)a[0]; r[1]=(_Float16)a[1]; r[2]=(_Float16)a[2]; r[3]=(_Float16)a[3];
    r[4]=(_Float16)b[0]; r[5]=(_Float16)b[1]; r[6]=(_Float16)b[2]; r[7]=(_Float16)b[3];
    return r;
}
// Liveness pin: value becomes opaque -> compiler cannot rematerialize the load.
__device__ __forceinline__ void pin(half4& x)  { asm volatile("" : "+v"(x)); }
__device__ __forceinline__ void pin(half8& x)  { asm volatile("" : "+v"(x)); }
__device__ __forceinline__ void pin(f32x4& x)  { asm volatile("" : "+v"(x)); }

// Swapped-operand GRU, 2 waves/block. Block tile = 16 batch rows x all 192
// gate cols; wave w owns gate cols [32w,32w+32) of each gate kind.
// D-frag(col=m,row=4kg+q) == B-frag(col=m,k=4kg+i) so each wave's own h-cols
// recycle lane-locally; sibling's 32 cols exchanged via tiny LDS buffer.
__global__ __launch_bounds__(128, 2) void gru_kernel(
    const float* __restrict__ data,   // [B,T,N,F]
    const float* __restrict__ h0,     // [B,N,H]
    const float* __restrict__ w_ih,   // [192,64]
    const float* __restrict__ w_hh,   // [192,64]
    const float* __restrict__ b_ih,   // [192]
    const float* __restrict__ b_hh,   // [192]
    float* __restrict__ out)          // [B,T,N,H] ++ [B,N,H]
{
    const int lane = threadIdx.x & 63;
    const int w    = threadIdx.x >> 6;   // 0 or 1
    const int sw   = 1 - w;
    const int cl   = lane & 15;          // batch row within tile (m); weight row (n) in A
    const int kg   = lane >> 4;          // k-group
    const int row0 = blockIdx.x * 16;

    const int m  = row0 + cl;
    const int mb = m / N_NODES, mn = m % N_NODES;
    const int xybase = mb * B_STRIDE + mn * 64;  // row base in data AND out

    __shared__ _Float16 hx[2][4][16][20];  // [buf][k-slice s4][m][16+4 pad]

    // ---- weights as swapped A-frags (lane: W[n = g*64 + w*32 + jt*16 + cl][k]) ----
    half8 wih[3][2][2];   // [gate][jt][s], k = 32s + 8kg + i
    half4 whh[3][2][4];   // [gate][jt][s], k = 16s + 4kg + i
#pragma unroll
    for (int g = 0; g < 3; ++g) {
#pragma unroll
        for (int jt = 0; jt < 2; ++jt) {
            const int n = g * 64 + w * 32 + jt * 16 + cl;
            const float* pih = w_ih + n * 64;
            const float* phh = w_hh + n * 64;
#pragma unroll
            for (int s = 0; s < 2; ++s)
                wih[g][jt][s] = cvt8(*(const f32x4*)(pih + s * 32 + kg * 8),
                                     *(const f32x4*)(pih + s * 32 + kg * 8 + 4));
#pragma unroll
            for (int s = 0; s < 4; ++s)
                whh[g][jt][s] = cvt4(*(const f32x4*)(phh + s * 16 + kg * 4));
        }
    }
    // ---- bias tiles in D layout (n = w*32 + jt*16 + 4kg + q) as MFMA C-init ----
    f32x4 bR[2], bZ[2], bNX[2], bNH[2];
#pragma unroll
    for (int jt = 0; jt < 2; ++jt) {
        const int o = w * 32 + jt * 16 + kg * 4;
        bR[jt]  = *(const f32x4*)(b_ih + o)       + *(const f32x4*)(b_hh + o);
        bZ[jt]  = *(const f32x4*)(b_ih + 64 + o)  + *(const f32x4*)(b_hh + 64 + o);
        bNX[jt] = *(const f32x4*)(b_ih + 128 + o);
        bNH[jt] = *(const f32x4*)(b_hh + 128 + o);
    }
    // pin everything loop-invariant
#pragma unroll
    for (int g = 0; g < 3; ++g)
#pragma unroll
        for (int jt = 0; jt < 2; ++jt) {
            pin(wih[g][jt][0]); pin(wih[g][jt][1]);
#pragma unroll
            for (int s = 0; s < 4; ++s) pin(whh[g][jt][s]);
        }
#pragma unroll
    for (int jt = 0; jt < 2; ++jt) { pin(bR[jt]); pin(bZ[jt]); pin(bNX[jt]); pin(bNH[jt]); }

    // ---- h state: own cols f32 + full f16 B-frags ----
    f32x4 hF[2];
    half4 hB[4];
#pragma unroll
    for (int jt = 0; jt < 2; ++jt) {
        hF[jt] = *(const f32x4*)(h0 + m * 64 + w * 32 + jt * 16 + kg * 4);
        hB[2 * w + jt] = cvt4(hF[jt]);
        *(half4*)&hx[0][2 * w + jt][cl][kg * 4] = hB[2 * w + jt];
    }
    __syncthreads();
#pragma unroll
    for (int jt = 0; jt < 2; ++jt)
        hB[2 * sw + jt] = *(const half4*)&hx[0][2 * sw + jt][cl][kg * 4];

    // ---- x: cur (f16) + prefetch t+1 in flight ----
    half8 xcur[2];
    {
        f32x4 t0[4];
#pragma unroll
        for (int q = 0; q < 4; ++q)
            t0[q] = *(const f32x4*)(data + xybase + (q >> 1) * 32 + kg * 8 + (q & 1) * 4);
        xcur[0] = cvt8(t0[0], t0[1]);
        xcur[1] = cvt8(t0[2], t0[3]);
    }
    f32x4 xpf[4];
#pragma unroll
    for (int q = 0; q < 4; ++q)
        xpf[q] = *(const f32x4*)(data + xybase + RS_T + (q >> 1) * 32 + kg * 8 + (q & 1) * 4);

#pragma unroll 1
    for (int t = 0; t < T_STEPS; ++t) {
        // arrived prefetch -> xnext; issue loads for t+2 (2-step flight time)
        half8 xnext[2];
        xnext[0] = cvt8(xpf[0], xpf[1]);
        xnext[1] = cvt8(xpf[2], xpf[3]);
        const int tl = (t + 2 < T_STEPS) ? t + 2 : T_STEPS - 1;
#pragma unroll
        for (int q = 0; q < 4; ++q)
            xpf[q] = *(const f32x4*)(data + xybase + tl * RS_T +
                                     (q >> 1) * 32 + kg * 8 + (q & 1) * 4);

        // ---- MFMAs (bias enters as C of first MFMA in each chain) ----
        f32x4 aR[2], aZ[2], aNX[2], aNH[2];
#pragma unroll
        for (int jt = 0; jt < 2; ++jt) {
            aR[jt]  = __builtin_amdgcn_mfma_f32_16x16x32_f16(wih[0][jt][0], xcur[0], bR[jt],  0, 0, 0);
            aZ[jt]  = __builtin_amdgcn_mfma_f32_16x16x32_f16(wih[1][jt][0], xcur[0], bZ[jt],  0, 0, 0);
            aNX[jt] = __builtin_amdgcn_mfma_f32_16x16x32_f16(wih[2][jt][0], xcur[0], bNX[jt], 0, 0, 0);
        }
#pragma unroll
        for (int jt = 0; jt < 2; ++jt) {
            aR[jt]  = __builtin_amdgcn_mfma_f32_16x16x32_f16(wih[0][jt][1], xcur[1], aR[jt],  0, 0, 0);
            aZ[jt]  = __builtin_amdgcn_mfma_f32_16x16x32_f16(wih[1][jt][1], xcur[1], aZ[jt],  0, 0, 0);
            aNX[jt] = __builtin_amdgcn_mfma_f32_16x16x32_f16(wih[2][jt][1], xcur[1], aNX[jt], 0, 0, 0);
        }
#pragma unroll
        for (int jt = 0; jt < 2; ++jt)
            aNH[jt] = __builtin_amdgcn_mfma_f32_16x16x16f16(whh[2][jt][0], hB[0], bNH[jt], 0, 0, 0);
#pragma unroll
        for (int s = 0; s < 4; ++s) {
#pragma unroll
            for (int jt = 0; jt < 2; ++jt) {
                aR[jt] = __builtin_amdgcn_mfma_f32_16x16x16f16(whh[0][jt][s], hB[s], aR[jt], 0, 0, 0);
                aZ[jt] = __builtin_amdgcn_mfma_f32_16x16x16f16(whh[1][jt][s], hB[s], aZ[jt], 0, 0, 0);
                if (s > 0)
                    aNH[jt] = __builtin_amdgcn_mfma_f32_16x16x16f16(whh[2][jt][s], hB[s], aNH[jt], 0, 0, 0);
            }
        }

        // ---- gates + state update + store (D layout, lane-local) ----
#pragma unroll
        for (int jt = 0; jt < 2; ++jt) {
            f32x4 hn;
#pragma unroll
            for (int q = 0; q < 4; ++q) {
                const float rg = fsigmoid(aR[jt][q]);
                const float zg = fsigmoid(aZ[jt][q]);
                const float cd = ftanh_f(aNX[jt][q] + rg * aNH[jt][q]);
                hn[q] = cd + zg * (hF[jt][q] - cd);
            }
            hF[jt] = hn;
            *(f32x4*)(out + xybase + t * RS_T + w * 32 + jt * 16 + kg * 4) = hn;
        }

        // ---- cross-wave h exchange (double-buffered, lgkm-only barrier) ----
        if (t + 1 < T_STEPS) {
            const int nb = (t + 1) & 1;
#pragma unroll
            for (int jt = 0; jt < 2; ++jt) {
                hB[2 * w + jt] = cvt4(hF[jt]);
                *(half4*)&hx[nb][2 * w + jt][cl][kg * 4] = hB[2 * w + jt];
            }
            asm volatile("s_waitcnt lgkmcnt(0)" ::: "memory");
            __builtin_amdgcn_s_barrier();
#pragma unroll
            for (int jt = 0; jt < 2; ++jt)
                hB[2 * sw + jt] = *(const half4*)&hx[nb][2 * sw + jt][cl][kg * 4];
        }
        xcur[0] = xnext[0];
        xcur[1] = xnext[1];
    }

    // h_last
#pragma unroll
    for (int jt = 0; jt < 2; ++jt)
        *(f32x4*)(out + HLAST_OFF + m * 64 + w * 32 + jt * 16 + kg * 4) = hF[jt];
}

extern "C" void kernel_launch(void* const* d_in, const int* in_sizes, int n_in,
                              void* d_out, int out_size, void* d_ws, size_t ws_size,
                              hipStream_t stream) {
    const float* data = (const float*)d_in[1];
    const float* h0   = (const float*)d_in[2];
    const float* w_ih = (const float*)d_in[3];
    const float* w_hh = (const float*)d_in[4];
    const float* b_ih = (const float*)d_in[5];
    const float* b_hh = (const float*)d_in[6];
    float* out = (float*)d_out;

    // 20800 rows / 16 per block, 2 waves per block
    gru_kernel<<<dim3(1300), dim3(128), 0, stream>>>(
        data, h0, w_ih, w_hh, b_ih, b_hh, out);
}

// Round 6
// 91.977 us; speedup vs baseline: 1.7693x; 1.7693x over previous
//
#include <hip/hip_runtime.h>

typedef __attribute__((ext_vector_type(4))) _Float16 half4;
typedef __attribute__((ext_vector_type(8))) _Float16 half8;
typedef __attribute__((ext_vector_type(4))) float f32x4;

#define T_STEPS 24
#define N_NODES 325
#define RS_T 20800       // N*H elements per t
#define B_STRIDE 499200  // T*N*H elements per b
#define HLAST_OFF 31948800

__device__ __forceinline__ float fsigmoid(float x) {
    return __builtin_amdgcn_rcpf(1.0f + __expf(-x));
}
__device__ __forceinline__ float ftanh_f(float x) {
    return 1.0f - 2.0f * __builtin_amdgcn_rcpf(1.0f + __expf(2.0f * x));
}
__device__ __forceinline__ half4 cvt4(f32x4 a) {
    half4 r;
    r[0] = (_Float16)a[0]; r[1] = (_Float16)a[1];
    r[2] = (_Float16)a[2]; r[3] = (_Float16)a[3];
    return r;
}
__device__ __forceinline__ half8 cvt8(f32x4 a, f32x4 b) {
    half8 r;
    r[0]=(_Float16)a[0]; r[1]=(_Float16)a[1]; r[2]=(_Float16)a[2]; r[3]=(_Float16)a[3];
    r[4]=(_Float16)b[0]; r[5]=(_Float16)b[1]; r[6]=(_Float16)b[2]; r[7]=(_Float16)b[3];
    return r;
}

// 4-wave block, 16 batch rows, wave wv owns gate cols [16wv,16wv+16) of each
// of the 3 gates. Weights live in LDS as f16 with XOR swizzle
// (byte ^= (row&7)<<4): B-frag ds_read_b128 is conflict-free (2-way max).
// h exchanged through swizzled LDS; barrier is lgkmcnt-only so the 2-step-deep
// x prefetch and the output stores stay in flight across steps.
__global__ __launch_bounds__(256, 3) void gru_lds_kernel(
    const float* __restrict__ data,   // [B,T,N,F]
    const float* __restrict__ h0,     // [B,N,H]
    const float* __restrict__ w_ih,   // [192,64]
    const float* __restrict__ w_hh,   // [192,64]
    const float* __restrict__ b_ih,   // [192]
    const float* __restrict__ b_hh,   // [192]
    float* __restrict__ out)          // [B,T,N,H] ++ [B,N,H]
{
    const int tid  = threadIdx.x;
    const int lane = tid & 63;
    const int wv   = tid >> 6;        // 0..3
    const int cl   = lane & 15;       // A-row (batch) / B-col (gate) / D-col
    const int kg   = lane >> 4;       // k-group
    const int c0   = wv * 16;
    const int row0 = blockIdx.x * 16;

    __shared__ __align__(16) char wlds[2][192 * 128]; // [ih,hh] f16 swizzled rows
    __shared__ __align__(16) char hlds[2][16 * 128];  // double-buffered h, f16 swizzled

    // ---- stage weights to LDS (f16, swizzled): 1536 half8-chunks per matrix ----
#pragma unroll
    for (int mat = 0; mat < 2; ++mat) {
        const float* src = (mat == 0) ? w_ih : w_hh;
#pragma unroll
        for (int it = 0; it < 6; ++it) {
            const int c = it * 256 + tid;         // 0..1535
            const int n = c >> 3, j = c & 7;      // row n, 8-el chunk j
            const f32x4 lo = *(const f32x4*)(src + n * 64 + j * 8);
            const f32x4 hi = *(const f32x4*)(src + n * 64 + j * 8 + 4);
            const int off = n * 128 + ((j * 16) ^ ((n & 7) << 4));
            *(half8*)(&wlds[mat][0] + off) = cvt8(lo, hi);
        }
    }

    // ---- stage h0 tile into hlds[0] (f16, swizzled) ----
    {
        const int m = tid >> 4, c4 = (tid & 15) * 4;   // 16 rows x 16 chunks of 4
        const f32x4 v = *(const f32x4*)(h0 + (row0 + m) * 64 + c4);
        const int off = m * 128 + ((c4 * 2) ^ ((m & 7) << 4));
        *(half4*)(&hlds[0][0] + off) = cvt4(v);
    }
    __syncthreads();

    // ---- loop-invariant LDS byte offsets ----
    const int wsw = ((c0 + cl) & 7) << 4;     // weight-row swizzle (same all gates)
    int woff[2][2];                           // [mat][s] base at gate 0; gates at +8192
#pragma unroll
    for (int s = 0; s < 2; ++s) {
        woff[0][s] = (c0 + cl) * 128 + ((s * 64 + kg * 16) ^ wsw);
        woff[1][s] = woff[0][s];
    }
    const int hroff0 = cl * 128 + ((      kg * 16) ^ ((cl & 7) << 4)); // s=0
    const int hroff1 = cl * 128 + ((64 +  kg * 16) ^ ((cl & 7) << 4)); // s=1

    // ---- bias splats as MFMA C-init (bias indexed by gate col n = c0+cl) ----
    const float bc0 = b_ih[      c0 + cl] + b_hh[      c0 + cl];
    const float bc1 = b_ih[ 64 + c0 + cl] + b_hh[ 64 + c0 + cl];
    const float bi2 = b_ih[128 + c0 + cl];
    const float bh2 = b_hh[128 + c0 + cl];
    const f32x4 bR4  = {bc0, bc0, bc0, bc0};
    const f32x4 bZ4  = {bc1, bc1, bc1, bc1};
    const f32x4 bNX4 = {bi2, bi2, bi2, bi2};
    const f32x4 bNH4 = {bh2, bh2, bh2, bh2};

    // ---- per-lane h master copy (D layout rows kg*4+r, col c0+cl) ----
    const int hb0 = (row0 + kg * 4) * 64 + c0 + cl;
    float hreg[4];
#pragma unroll
    for (int r = 0; r < 4; ++r) hreg[r] = h0[hb0 + 64 * r];

    // ---- addressing for x loads and out stores ----
    const int xrow = row0 + cl;
    const int xb = xrow / N_NODES, xn = xrow % N_NODES;
    const int xbase = xb * B_STRIDE + xn * 64;
    int obase[4];
#pragma unroll
    for (int r = 0; r < 4; ++r) {
        const int row = row0 + kg * 4 + r;
        const int b = row / N_NODES, n = row % N_NODES;
        obase[r] = b * B_STRIDE + n * 64 + c0 + cl;
    }

    // ---- x: t=0 current + t=1 prefetch in flight ----
    half8 xcur[2];
    {
        f32x4 t0[4];
#pragma unroll
        for (int q = 0; q < 4; ++q)
            t0[q] = *(const f32x4*)(data + xbase + (q >> 1) * 32 + kg * 8 + (q & 1) * 4);
        xcur[0] = cvt8(t0[0], t0[1]);
        xcur[1] = cvt8(t0[2], t0[3]);
    }
    f32x4 xpf[4];
#pragma unroll
    for (int q = 0; q < 4; ++q)
        xpf[q] = *(const f32x4*)(data + xbase + RS_T + (q >> 1) * 32 + kg * 8 + (q & 1) * 4);

#pragma unroll 1
    for (int t = 0; t < T_STEPS; ++t) {
        const int cb = t & 1;

        // h A-frags from LDS (published by previous step's barrier)
        half8 hA0 = *(const half8*)(&hlds[cb][0] + hroff0);
        half8 hA1 = *(const half8*)(&hlds[cb][0] + hroff1);

        // weight B-frags from LDS (conflict-free swizzled b128)
        half8 wr0 = *(const half8*)(&wlds[0][0] + woff[0][0]);
        half8 wr1 = *(const half8*)(&wlds[0][0] + woff[0][1]);
        half8 wz0 = *(const half8*)(&wlds[0][0] + woff[0][0] + 8192);
        half8 wz1 = *(const half8*)(&wlds[0][0] + woff[0][1] + 8192);
        half8 wn0 = *(const half8*)(&wlds[0][0] + woff[0][0] + 16384);
        half8 wn1 = *(const half8*)(&wlds[0][0] + woff[0][1] + 16384);
        half8 ur0 = *(const half8*)(&wlds[1][0] + woff[1][0]);
        half8 ur1 = *(const half8*)(&wlds[1][0] + woff[1][1]);
        half8 uz0 = *(const half8*)(&wlds[1][0] + woff[1][0] + 8192);
        half8 uz1 = *(const half8*)(&wlds[1][0] + woff[1][1] + 8192);
        half8 un0 = *(const half8*)(&wlds[1][0] + woff[1][0] + 16384);
        half8 un1 = *(const half8*)(&wlds[1][0] + woff[1][1] + 16384);

        // next x arrives; issue t+2 prefetch
        half8 xnext[2];
        xnext[0] = cvt8(xpf[0], xpf[1]);
        xnext[1] = cvt8(xpf[2], xpf[3]);
        const int tl = (t + 2 < T_STEPS) ? t + 2 : T_STEPS - 1;
#pragma unroll
        for (int q = 0; q < 4; ++q)
            xpf[q] = *(const f32x4*)(data + xbase + tl * RS_T +
                                     (q >> 1) * 32 + kg * 8 + (q & 1) * 4);

        // ---- 12 MFMAs (bias pre-loaded via C) ----
        f32x4 aR  = __builtin_amdgcn_mfma_f32_16x16x32_f16(xcur[0], wr0, bR4,  0, 0, 0);
        f32x4 aZ  = __builtin_amdgcn_mfma_f32_16x16x32_f16(xcur[0], wz0, bZ4,  0, 0, 0);
        f32x4 aNX = __builtin_amdgcn_mfma_f32_16x16x32_f16(xcur[0], wn0, bNX4, 0, 0, 0);
        f32x4 aNH = __builtin_amdgcn_mfma_f32_16x16x32_f16(hA0,     un0, bNH4, 0, 0, 0);
        aR  = __builtin_amdgcn_mfma_f32_16x16x32_f16(xcur[1], wr1, aR,  0, 0, 0);
        aZ  = __builtin_amdgcn_mfma_f32_16x16x32_f16(xcur[1], wz1, aZ,  0, 0, 0);
        aNX = __builtin_amdgcn_mfma_f32_16x16x32_f16(xcur[1], wn1, aNX, 0, 0, 0);
        aNH = __builtin_amdgcn_mfma_f32_16x16x32_f16(hA1,     un1, aNH, 0, 0, 0);
        aR  = __builtin_amdgcn_mfma_f32_16x16x32_f16(hA0,     ur0, aR,  0, 0, 0);
        aZ  = __builtin_amdgcn_mfma_f32_16x16x32_f16(hA0,     uz0, aZ,  0, 0, 0);
        aR  = __builtin_amdgcn_mfma_f32_16x16x32_f16(hA1,     ur1, aR,  0, 0, 0);
        aZ  = __builtin_amdgcn_mfma_f32_16x16x32_f16(hA1,     uz1, aZ,  0, 0, 0);

        // ---- gates + update + store ----
        float hn[4];
#pragma unroll
        for (int r = 0; r < 4; ++r) {
            const float rg = fsigmoid(aR[r]);
            const float zg = fsigmoid(aZ[r]);
            const float cd = ftanh_f(aNX[r] + rg * aNH[r]);
            hn[r] = cd + zg * (hreg[r] - cd);
            hreg[r] = hn[r];
            out[t * RS_T + obase[r]] = hn[r];
        }

        // ---- publish h for t+1 (swizzled f16 scalar writes), lgkm-only barrier ----
        if (t + 1 < T_STEPS) {
            const int nb = (t + 1) & 1;
#pragma unroll
            for (int r = 0; r < 4; ++r) {
                const int mrow = kg * 4 + r;
                const int off = mrow * 128 + (((c0 + cl) * 2) ^ ((mrow & 7) << 4));
                *(_Float16*)(&hlds[nb][0] + off) = (_Float16)hn[r];
            }
            asm volatile("s_waitcnt lgkmcnt(0)" ::: "memory");
            __builtin_amdgcn_s_barrier();
            __builtin_amdgcn_sched_barrier(0);
        }
        xcur[0] = xnext[0];
        xcur[1] = xnext[1];
    }

    // h_last
#pragma unroll
    for (int r = 0; r < 4; ++r)
        out[HLAST_OFF + hb0 + 64 * r] = hreg[r];
}

extern "C" void kernel_launch(void* const* d_in, const int* in_sizes, int n_in,
                              void* d_out, int out_size, void* d_ws, size_t ws_size,
                              hipStream_t stream) {
    const float* data = (const float*)d_in[1];
    const float* h0   = (const float*)d_in[2];
    const float* w_ih = (const float*)d_in[3];
    const float* w_hh = (const float*)d_in[4];
    const float* b_ih = (const float*)d_in[5];
    const float* b_hh = (const float*)d_in[6];
    float* out = (float*)d_out;

    // 20800 rows / 16 per block = 1300 blocks, 4 waves each
    gru_lds_kernel<<<dim3(1300), dim3(256), 0, stream>>>(
        data, h0, w_ih, w_hh, b_ih, b_hh, out);
}